// Round 2
// baseline (912.326 us; speedup 1.0000x reference)
//
#include <hip/hip_runtime.h>
#include <math.h>

typedef __attribute__((ext_vector_type(8))) short bf16x8;
typedef __attribute__((ext_vector_type(4))) short bf16x4;
typedef __attribute__((ext_vector_type(2))) short bf16x2;
typedef __attribute__((ext_vector_type(4))) float f32x4;

#define NH 12
#define HD 64
#define C0 768
#define C3 2304
#define LS 256

static __device__ __forceinline__ float bf2f(short u) {
  union { unsigned int i; float f; } c;
  c.i = ((unsigned int)(unsigned short)u) << 16;
  return c.f;
}
static __device__ __forceinline__ short f2bf(float f) {
  union { float f; unsigned int i; } c; c.f = f;
  unsigned int x = c.i;
  x += 0x7fffu + ((x >> 16) & 1u);
  return (short)(x >> 16);
}

// ---------------- cast fp32 -> bf16 (vectorized) ----------------
__global__ __launch_bounds__(256) void cast_kernel(const float* __restrict__ in,
                                                   short* __restrict__ out, int nquads) {
  int i = blockIdx.x * blockDim.x + threadIdx.x;
  int stride = gridDim.x * blockDim.x;
  for (; i < nquads; i += stride) {
    float4 v = ((const float4*)in)[i];
    bf16x4 o = { f2bf(v.x), f2bf(v.y), f2bf(v.z), f2bf(v.w) };
    ((bf16x4*)out)[i] = o;
  }
}

// ---------------- RoPE table: cos/sin for t in [0,256), d in [0,64) ----------------
__global__ void rope_tab_kernel(float* __restrict__ cost, float* __restrict__ sint) {
  int t = blockIdx.x, d = threadIdx.x;
  int i = d & 31;  // pos index: d<32 -> d, d>=32 -> d-32
  float freq = powf(10000.0f, -(float)(4 * i + 1) / 64.0f);
  float th = (float)t * freq;
  cost[t * 64 + d] = cosf(th);
  sint[t * 64 + d] = sinf(th);
}

// ---------------- bf16 MFMA GEMM: A(MxK) row-major, B(KxN) row-major ----------------
// 128x128 tile, BK=32, 4 waves (2x2), each wave 64x64 = 4x4 frags of 16x16x32.
template <int OUT_F32>
__global__ __launch_bounds__(256) void gemm_kernel(const short* __restrict__ A,
                                                   const short* __restrict__ B,
                                                   void* __restrict__ Cout,
                                                   int M, int N, int K) {
  __shared__ short As[128][40];  // row stride 80B = 20 words: rows 2-way alias (free)
  __shared__ short Bt[128][40];  // [n][k] transposed, same padding
  int bn = blockIdx.x, bm = blockIdx.y;
  int tid = threadIdx.x, lane = tid & 63, wave = tid >> 6;
  int lr = lane & 15, lg = lane >> 4;
  int wm = (wave >> 1) * 64, wn = (wave & 1) * 64;
  long arow0 = (long)bm * 128;
  long bcol0 = (long)bn * 128;

  f32x4 zero4 = {0.f, 0.f, 0.f, 0.f};
  f32x4 acc[4][4];
#pragma unroll
  for (int m = 0; m < 4; ++m)
#pragma unroll
    for (int n = 0; n < 4; ++n) acc[m][n] = zero4;

  for (int k0 = 0; k0 < K; k0 += 32) {
    // stage A: 128x32
#pragma unroll
    for (int i = 0; i < 2; ++i) {
      int e = tid * 8 + i * 2048;
      int r = e >> 5, c = e & 31;
      *(bf16x8*)&As[r][c] = *(const bf16x8*)&A[(arow0 + r) * K + k0 + c];
    }
    // stage B transposed: 32x128 -> Bt[n][k]
#pragma unroll
    for (int i = 0; i < 2; ++i) {
      int e = tid * 8 + i * 2048;
      int rk = e >> 7, cn = e & 127;
      bf16x8 v = *(const bf16x8*)&B[(long)(k0 + rk) * N + bcol0 + cn];
#pragma unroll
      for (int j = 0; j < 8; ++j) Bt[cn + j][rk] = v[j];
    }
    __syncthreads();
    bf16x8 af[4], bfr[4];
#pragma unroll
    for (int m = 0; m < 4; ++m) af[m] = *(bf16x8*)&As[wm + m * 16 + lr][lg * 8];
#pragma unroll
    for (int n = 0; n < 4; ++n) bfr[n] = *(bf16x8*)&Bt[wn + n * 16 + lr][lg * 8];
#pragma unroll
    for (int m = 0; m < 4; ++m)
#pragma unroll
      for (int n = 0; n < 4; ++n)
        acc[m][n] = __builtin_amdgcn_mfma_f32_16x16x32_bf16(af[m], bfr[n], acc[m][n], 0, 0, 0);
    __syncthreads();
  }
  // epilogue: D layout col=lane&15, row=(lane>>4)*4+r
#pragma unroll
  for (int m = 0; m < 4; ++m)
#pragma unroll
    for (int n = 0; n < 4; ++n)
#pragma unroll
      for (int r = 0; r < 4; ++r) {
        long row = arow0 + wm + m * 16 + lg * 4 + r;
        long col = bcol0 + wn + n * 16 + lr;
        float v = acc[m][n][r];
        if (OUT_F32) ((float*)Cout)[row * N + col] = v;
        else ((short*)Cout)[row * N + col] = f2bf(v);
      }
}

// ---------------- fused RMSNorm(q,k over C=768) + RoPE, in place on QKV ----------------
__global__ __launch_bounds__(384) void norm_rope_kernel(short* __restrict__ QKV,
    const float* __restrict__ w_ln, const float* __restrict__ cost,
    const float* __restrict__ sint) {
  int row = blockIdx.x;       // 0..32767
  int t = row & 255;          // position within causal block
  int i = threadIdx.x;        // pair index 0..383
  long base = (long)row * C3;
  bf16x2 q2 = *(bf16x2*)&QKV[base + 2 * i];
  bf16x2 k2 = *(bf16x2*)&QKV[base + C0 + 2 * i];
  float qa = bf2f(q2.x), qb = bf2f(q2.y);
  float ka = bf2f(k2.x), kb = bf2f(k2.y);
  float sq = qa * qa + qb * qb;
  float sk = ka * ka + kb * kb;
#pragma unroll
  for (int o = 32; o > 0; o >>= 1) {
    sq += __shfl_down(sq, o);
    sk += __shfl_down(sk, o);
  }
  __shared__ float red[2][6];
  int wv = i >> 6;
  if ((i & 63) == 0) { red[0][wv] = sq; red[1][wv] = sk; }
  __syncthreads();
  float s0 = 0.f, s1 = 0.f;
#pragma unroll
  for (int w = 0; w < 6; ++w) { s0 += red[0][w]; s1 += red[1][w]; }
  float rq = rsqrtf(s0 * (1.0f / 768.0f) + 1e-6f);
  float rk = rsqrtf(s1 * (1.0f / 768.0f) + 1e-6f);
  float wl0 = w_ln[2 * i], wl1 = w_ln[2 * i + 1];
  float qn0 = qa * rq * wl0, qn1 = qb * rq * wl1;
  float kn0 = ka * rk * wl0, kn1 = kb * rk * wl1;
  int d0 = (2 * i) & 63;  // head-local dim of first pair element
  float c0 = cost[t * 64 + d0], c1 = cost[t * 64 + d0 + 1];
  float s0r = sint[t * 64 + d0], s1r = sint[t * 64 + d0 + 1];
  // out[2i] = x[2i]*cos - x[2i+1]*sin ; out[2i+1] = x[2i+1]*cos + x[2i]*sin
  bf16x2 qo, ko;
  qo.x = f2bf(qn0 * c0 - qn1 * s0r);
  qo.y = f2bf(qn1 * c1 + qn0 * s1r);
  ko.x = f2bf(kn0 * c0 - kn1 * s0r);
  ko.y = f2bf(kn1 * c1 + kn0 * s1r);
  *(bf16x2*)&QKV[base + 2 * i] = qo;
  *(bf16x2*)&QKV[base + C0 + 2 * i] = ko;
}

// ---------------- block-causal attention: one block per (bg, head) ----------------
// Q,K,V are 256x64 bf16 slices of QKV. S=QK^T/8 masked causal, softmax, Y=PV.
__global__ __launch_bounds__(256) void attn_kernel(const short* __restrict__ QKV,
                                                   short* __restrict__ Y) {
  __shared__ short Vt[64 * 256];     // V transposed [n][k], 16B-chunk XOR swizzle
  __shared__ short P[4][16 * 256];   // per-wave P tile [r][c], same swizzle
  int blk = blockIdx.x;
  int bg = blk / NH, h = blk % NH;
  const long base = (long)bg * LS * C3 + h * HD;
  int tid = threadIdx.x, lane = tid & 63, wave = tid >> 6;
  int lr = lane & 15, lg = lane >> 4;

  // stage V transposed + swizzled: elem (n,k) at n*256 + ((k>>3)^(n&7))*8 + (k&7)
#pragma unroll
  for (int it = 0; it < 16; ++it) {
    int e = tid * 4 + it * 1024;
    int k = e >> 6, n = e & 63;
    bf16x4 v = *(const bf16x4*)&QKV[base + (long)k * C3 + 2 * C0 + n];
#pragma unroll
    for (int j = 0; j < 4; ++j) {
      int nn = n + j;
      Vt[nn * 256 + (((k >> 3) ^ (nn & 7)) << 3) + (k & 7)] = v[j];
    }
  }

  // preload K fragments: B-operand of S = Q K^T (col = n*16+lr, k-dim contiguous)
  bf16x8 kf[16][2];
#pragma unroll
  for (int n = 0; n < 16; ++n)
#pragma unroll
    for (int ks = 0; ks < 2; ++ks)
      kf[n][ks] = *(const bf16x8*)&QKV[base + (long)(n * 16 + lr) * C3 + C0 + ks * 32 + lg * 8];

  __syncthreads();

  short* Pw = P[wave];

  for (int tt = 0; tt < 4; ++tt) {
    int tile = wave + tt * 4;   // row-tile index 0..15 (16 q rows each)
    int m0 = tile * 16;
    bf16x8 qf[2];
#pragma unroll
    for (int ks = 0; ks < 2; ++ks)
      qf[ks] = *(const bf16x8*)&QKV[base + (long)(m0 + lr) * C3 + ks * 32 + lg * 8];

    f32x4 zero4 = {0.f, 0.f, 0.f, 0.f};
    f32x4 accs[16];
#pragma unroll
    for (int n = 0; n < 16; ++n) accs[n] = zero4;

#pragma unroll
    for (int n = 0; n < 16; ++n) {
      if (n <= tile) {  // wave-uniform guard: fully-masked col tiles skipped
        accs[n] = __builtin_amdgcn_mfma_f32_16x16x32_bf16(qf[0], kf[n][0], accs[n], 0, 0, 0);
        accs[n] = __builtin_amdgcn_mfma_f32_16x16x32_bf16(qf[1], kf[n][1], accs[n], 0, 0, 0);
      }
    }

    // softmax per row (rows live in 16-lane groups: row = lg*4 + r)
    float lsum[4];
#pragma unroll
    for (int r = 0; r < 4; ++r) {
      int qrow = m0 + lg * 4 + r;
      float m = -1e30f;
#pragma unroll
      for (int n = 0; n < 16; ++n) {
        if (n <= tile) {
          int col = n * 16 + lr;
          float v = accs[n][r] * 0.125f;
          v = (col <= qrow) ? v : -1e30f;
          accs[n][r] = v;
          m = fmaxf(m, v);
        }
      }
#pragma unroll
      for (int o = 1; o < 16; o <<= 1) m = fmaxf(m, __shfl_xor(m, o));
      float s = 0.f;
#pragma unroll
      for (int n = 0; n < 16; ++n) {
        if (n <= tile) {
          float p = __expf(accs[n][r] - m);
          accs[n][r] = p;
          s += p;
        }
      }
#pragma unroll
      for (int o = 1; o < 16; o <<= 1) s += __shfl_xor(s, o);
      lsum[r] = s;
    }

    // write P to swizzled LDS.
    // PV reads whole 32-wide k chunks up to ktmax -> must zero-fill cols in
    // [ (tile+1)*16, 2*(ktmax+1)*16 ).  (Round-1 bug: even tiles read one
    // never-written 16-col tile of garbage LDS -> absmax ~8.5.)
    int ktmax = (tile * 16 + 15) >> 5;
    int nlim = 2 * (ktmax + 1);   // exact P column-tile range PV will read
#pragma unroll
    for (int n = 0; n < 16; ++n) {
      if (n < nlim) {
#pragma unroll
        for (int r = 0; r < 4; ++r) {
          int rr = lg * 4 + r, cc = n * 16 + lr;
          float pv = (n <= tile) ? accs[n][r] : 0.0f;
          Pw[rr * 256 + (((cc >> 3) ^ (rr & 7)) << 3) + (cc & 7)] = f2bf(pv);
        }
      }
    }
    asm volatile("s_waitcnt lgkmcnt(0)" ::: "memory");
    __builtin_amdgcn_sched_barrier(0);

    // Y = P @ V ; causal limits k-range
    f32x4 yacc[4];
#pragma unroll
    for (int n2 = 0; n2 < 4; ++n2) yacc[n2] = zero4;
#pragma unroll
    for (int kt = 0; kt < 8; ++kt) {
      if (kt <= ktmax) {
        int ac = kt * 32 + lg * 8;  // k offset, multiple of 8
        bf16x8 pa = *(bf16x8*)&Pw[lr * 256 + (((ac >> 3) ^ (lr & 7)) << 3)];
#pragma unroll
        for (int n2 = 0; n2 < 4; ++n2) {
          int vn = n2 * 16 + lr;
          bf16x8 vb = *(bf16x8*)&Vt[vn * 256 + (((ac >> 3) ^ (vn & 7)) << 3)];
          yacc[n2] = __builtin_amdgcn_mfma_f32_16x16x32_bf16(pa, vb, yacc[n2], 0, 0, 0);
        }
      }
    }

    // epilogue: divide by softmax denom, write Y (merged-heads layout)
#pragma unroll
    for (int n2 = 0; n2 < 4; ++n2) {
#pragma unroll
      for (int r = 0; r < 4; ++r) {
        int row = m0 + lg * 4 + r, d = n2 * 16 + lr;
        float yv = yacc[n2][r] / lsum[r];
        Y[((long)(bg * LS + row)) * C0 + h * HD + d] = f2bf(yv);
      }
    }
    // P reads must complete before next iteration overwrites
    asm volatile("s_waitcnt lgkmcnt(0)" ::: "memory");
    __builtin_amdgcn_sched_barrier(0);
  }
}

extern "C" void kernel_launch(void* const* d_in, const int* in_sizes, int n_in,
                              void* d_out, int out_size, void* d_ws, size_t ws_size,
                              hipStream_t stream) {
  (void)in_sizes; (void)n_in; (void)out_size; (void)ws_size;
  const float* x = (const float*)d_in[0];
  const float* w_qkv = (const float*)d_in[1];
  const float* w_ln = (const float*)d_in[2];
  const float* w_proj = (const float*)d_in[3];
  float* out = (float*)d_out;

  char* ws = (char*)d_ws;
  // ws layout (bytes)
  short* Xb     = (short*)(ws + 0);                    // 32768*768*2   = 50331648
  short* QKV    = (short*)(ws + 50331648);             // 32768*2304*2  = 150994944
  short* Yb     = (short*)(ws + 201326592);            // 32768*768*2   = 50331648
  short* Wqkvb  = (short*)(ws + 251658240);            // 768*2304*2    = 3538944
  short* Wprojb = (short*)(ws + 255197184);            // 768*768*2     = 1179648
  float* cost   = (float*)(ws + 256376832);            // 256*64*4      = 65536
  float* sint   = (float*)(ws + 256442368);            // 65536

  cast_kernel<<<2048, 256, 0, stream>>>(x, Xb, (4 * 8192 * C0) / 4);
  cast_kernel<<<1024, 256, 0, stream>>>(w_qkv, Wqkvb, (C0 * C3) / 4);
  cast_kernel<<<512, 256, 0, stream>>>(w_proj, Wprojb, (C0 * C0) / 4);
  rope_tab_kernel<<<256, 64, 0, stream>>>(cost, sint);

  // QKV = X @ Wqkv  (32768 x 768 x 2304)
  gemm_kernel<0><<<dim3(C3 / 128, 32768 / 128), 256, 0, stream>>>(Xb, Wqkvb, QKV,
                                                                  32768, C3, C0);
  // RMSNorm(q,k) + RoPE, in place
  norm_rope_kernel<<<32768, 384, 0, stream>>>(QKV, w_ln, cost, sint);
  // block-causal attention
  attn_kernel<<<128 * NH, 256, 0, stream>>>(QKV, Yb);
  // out = Y @ Wproj (fp32 out)
  gemm_kernel<1><<<dim3(C0 / 128, 32768 / 128), 256, 0, stream>>>(Yb, Wprojb, out,
                                                                  32768, C0, C0);
}

// Round 3
// 478.815 us; speedup vs baseline: 1.9054x; 1.9054x over previous
//
#include <hip/hip_runtime.h>
#include <math.h>

typedef __attribute__((ext_vector_type(8))) short bf16x8;
typedef __attribute__((ext_vector_type(4))) short bf16x4;
typedef __attribute__((ext_vector_type(2))) short bf16x2;
typedef __attribute__((ext_vector_type(4))) float f32x4;

#define NH 12
#define HD 64
#define C0 768
#define C3 2304
#define LS 256

static __device__ __forceinline__ float bf2f(short u) {
  union { unsigned int i; float f; } c;
  c.i = ((unsigned int)(unsigned short)u) << 16;
  return c.f;
}
static __device__ __forceinline__ short f2bf(float f) {
  union { float f; unsigned int i; } c; c.f = f;
  unsigned int x = c.i;
  x += 0x7fffu + ((x >> 16) & 1u);
  return (short)(x >> 16);
}

// async global->LDS, 16B per lane; LDS dest is wave-uniform base + lane*16
static __device__ __forceinline__ void gload_lds16(const short* g, const short* l) {
  unsigned long long ga = (unsigned long long)g;
  unsigned int la = (unsigned int)(unsigned long long)l;  // low 32 bits = LDS offset
  __builtin_amdgcn_global_load_lds(
      (const __attribute__((address_space(1))) void*)ga,
      (__attribute__((address_space(3))) void*)la, 16, 0, 0);
}

// ---------------- cast fp32 -> bf16 (vectorized) ----------------
__global__ __launch_bounds__(256) void cast_kernel(const float* __restrict__ in,
                                                   short* __restrict__ out, int nquads) {
  int i = blockIdx.x * blockDim.x + threadIdx.x;
  int stride = gridDim.x * blockDim.x;
  for (; i < nquads; i += stride) {
    float4 v = ((const float4*)in)[i];
    bf16x4 o = { f2bf(v.x), f2bf(v.y), f2bf(v.z), f2bf(v.w) };
    ((bf16x4*)out)[i] = o;
  }
}

// ---------------- cast + transpose: in[K][N] fp32 -> out[N][K] bf16 ----------------
__global__ __launch_bounds__(256) void cast_transpose_kernel(const float* __restrict__ in,
                                                             short* __restrict__ out,
                                                             int K, int N) {
  __shared__ float tile[32][33];
  int n0 = blockIdx.x * 32, k0 = blockIdx.y * 32;
  int tx = threadIdx.x & 31, ty = threadIdx.x >> 5;  // 32 x 8
#pragma unroll
  for (int i = 0; i < 32; i += 8)
    tile[ty + i][tx] = in[(long)(k0 + ty + i) * N + n0 + tx];
  __syncthreads();
#pragma unroll
  for (int i = 0; i < 32; i += 8)
    out[(long)(n0 + ty + i) * K + k0 + tx] = f2bf(tile[tx][ty + i]);
}

// ---------------- RoPE table: cos/sin for t in [0,256), d in [0,64) ----------------
__global__ void rope_tab_kernel(float* __restrict__ cost, float* __restrict__ sint) {
  int t = blockIdx.x, d = threadIdx.x;
  int i = d & 31;  // pos index: d<32 -> d, d>=32 -> d-32
  float freq = powf(10000.0f, -(float)(4 * i + 1) / 64.0f);
  float th = (float)t * freq;
  cost[t * 64 + d] = cosf(th);
  sint[t * 64 + d] = sinf(th);
}

// ---------------- bf16 MFMA GEMM (m97 structure): A[M][K], Bt[N][K], both row-major
// 128x128 tile, BK=64, 4 waves (2x2), wave 64x64 = 4x4 frags of 16x16x32.
// Staging: global_load_lds w16 into LINEAR LDS; global source chunk pre-swizzled
// c = c' ^ (row&7); ds_read_b128 applies the same XOR -> conflict-free (both-sides rule).
template <int OUT_F32>
__global__ __launch_bounds__(256) void gemm_kernel(const short* __restrict__ A,
                                                   const short* __restrict__ Bt,
                                                   void* __restrict__ Cout,
                                                   int N, int K) {
  __shared__ short As[128 * 64];  // 16 KB, linear [row][64]
  __shared__ short Bs[128 * 64];  // 16 KB
  int bn = blockIdx.x, bm = blockIdx.y;
  int t = threadIdx.x, lane = t & 63, wave = t >> 6;
  int lr = lane & 15, lg = lane >> 4;
  int wm = (wave >> 1) * 64, wn = (wave & 1) * 64;
  const short* Abase = A + (long)bm * 128 * K;
  const short* Bbase = Bt + (long)bn * 128 * K;

  f32x4 zero4 = {0.f, 0.f, 0.f, 0.f};
  f32x4 acc[4][4];
#pragma unroll
  for (int m = 0; m < 4; ++m)
#pragma unroll
    for (int n = 0; n < 4; ++n) acc[m][n] = zero4;

  // precompute per-thread staging coords: chunk q = i*256 + t
  int srow[4], scol[4];
#pragma unroll
  for (int i = 0; i < 4; ++i) {
    int q = i * 256 + t;
    int r = q >> 3, cp = q & 7;
    srow[i] = r;
    scol[i] = (cp ^ (r & 7)) * 8;
  }

  for (int kt = 0; kt < K / 64; ++kt) {
    int k0 = kt * 64;
#pragma unroll
    for (int i = 0; i < 4; ++i) {
      int q = i * 256 + t;
      gload_lds16(Abase + (long)srow[i] * K + k0 + scol[i], &As[q * 8]);
      gload_lds16(Bbase + (long)srow[i] * K + k0 + scol[i], &Bs[q * 8]);
    }
    asm volatile("s_waitcnt vmcnt(0)" ::: "memory");
    __syncthreads();

#pragma unroll
    for (int s = 0; s < 2; ++s) {
      bf16x8 af[4], bfv[4];
#pragma unroll
      for (int m = 0; m < 4; ++m) {
        int row = wm + m * 16 + lr;
        af[m] = *(bf16x8*)&As[row * 64 + (((s * 4 + lg) ^ (row & 7)) << 3)];
      }
#pragma unroll
      for (int n = 0; n < 4; ++n) {
        int row = wn + n * 16 + lr;
        bfv[n] = *(bf16x8*)&Bs[row * 64 + (((s * 4 + lg) ^ (row & 7)) << 3)];
      }
#pragma unroll
      for (int m = 0; m < 4; ++m)
#pragma unroll
        for (int n = 0; n < 4; ++n)
          acc[m][n] = __builtin_amdgcn_mfma_f32_16x16x32_bf16(af[m], bfv[n], acc[m][n], 0, 0, 0);
    }
    __syncthreads();
  }

  // epilogue: D layout col=lane&15, row=(lane>>4)*4+r
  long crow0 = (long)bm * 128 + wm;
  long ccol0 = (long)bn * 128 + wn;
#pragma unroll
  for (int m = 0; m < 4; ++m)
#pragma unroll
    for (int n = 0; n < 4; ++n)
#pragma unroll
      for (int r = 0; r < 4; ++r) {
        long row = crow0 + m * 16 + lg * 4 + r;
        long col = ccol0 + n * 16 + lr;
        float v = acc[m][n][r];
        if (OUT_F32) ((float*)Cout)[row * N + col] = v;
        else ((short*)Cout)[row * N + col] = f2bf(v);
      }
}

// ---------------- fused RMSNorm(q,k over C=768) + RoPE, in place on QKV ----------------
__global__ __launch_bounds__(384) void norm_rope_kernel(short* __restrict__ QKV,
    const float* __restrict__ w_ln, const float* __restrict__ cost,
    const float* __restrict__ sint) {
  int row = blockIdx.x;       // 0..32767
  int t = row & 255;          // position within causal block
  int i = threadIdx.x;        // pair index 0..383
  long base = (long)row * C3;
  bf16x2 q2 = *(bf16x2*)&QKV[base + 2 * i];
  bf16x2 k2 = *(bf16x2*)&QKV[base + C0 + 2 * i];
  float qa = bf2f(q2.x), qb = bf2f(q2.y);
  float ka = bf2f(k2.x), kb = bf2f(k2.y);
  float sq = qa * qa + qb * qb;
  float sk = ka * ka + kb * kb;
#pragma unroll
  for (int o = 32; o > 0; o >>= 1) {
    sq += __shfl_down(sq, o);
    sk += __shfl_down(sk, o);
  }
  __shared__ float red[2][6];
  int wv = i >> 6;
  if ((i & 63) == 0) { red[0][wv] = sq; red[1][wv] = sk; }
  __syncthreads();
  float s0 = 0.f, s1 = 0.f;
#pragma unroll
  for (int w = 0; w < 6; ++w) { s0 += red[0][w]; s1 += red[1][w]; }
  float rq = rsqrtf(s0 * (1.0f / 768.0f) + 1e-6f);
  float rk = rsqrtf(s1 * (1.0f / 768.0f) + 1e-6f);
  float wl0 = w_ln[2 * i], wl1 = w_ln[2 * i + 1];
  float qn0 = qa * rq * wl0, qn1 = qb * rq * wl1;
  float kn0 = ka * rk * wl0, kn1 = kb * rk * wl1;
  int d0 = (2 * i) & 63;  // head-local dim of first pair element
  float c0 = cost[t * 64 + d0], c1 = cost[t * 64 + d0 + 1];
  float s0r = sint[t * 64 + d0], s1r = sint[t * 64 + d0 + 1];
  bf16x2 qo, ko;
  qo.x = f2bf(qn0 * c0 - qn1 * s0r);
  qo.y = f2bf(qn1 * c1 + qn0 * s1r);
  ko.x = f2bf(kn0 * c0 - kn1 * s0r);
  ko.y = f2bf(kn1 * c1 + kn0 * s1r);
  *(bf16x2*)&QKV[base + 2 * i] = qo;
  *(bf16x2*)&QKV[base + C0 + 2 * i] = ko;
}

// ---------------- block-causal attention: one block per (bg, head) ----------------
__global__ __launch_bounds__(256) void attn_kernel(const short* __restrict__ QKV,
                                                   short* __restrict__ Y) {
  __shared__ short Vt[64 * 256];     // V transposed [n][k], 16B-chunk XOR swizzle
  __shared__ short P[4][16 * 256];   // per-wave P tile [r][c], same swizzle
  int blk = blockIdx.x;
  int bg = blk / NH, h = blk % NH;
  const long base = (long)bg * LS * C3 + h * HD;
  int tid = threadIdx.x, lane = tid & 63, wave = tid >> 6;
  int lr = lane & 15, lg = lane >> 4;

#pragma unroll
  for (int it = 0; it < 16; ++it) {
    int e = tid * 4 + it * 1024;
    int k = e >> 6, n = e & 63;
    bf16x4 v = *(const bf16x4*)&QKV[base + (long)k * C3 + 2 * C0 + n];
#pragma unroll
    for (int j = 0; j < 4; ++j) {
      int nn = n + j;
      Vt[nn * 256 + (((k >> 3) ^ (nn & 7)) << 3) + (k & 7)] = v[j];
    }
  }

  bf16x8 kf[16][2];
#pragma unroll
  for (int n = 0; n < 16; ++n)
#pragma unroll
    for (int ks = 0; ks < 2; ++ks)
      kf[n][ks] = *(const bf16x8*)&QKV[base + (long)(n * 16 + lr) * C3 + C0 + ks * 32 + lg * 8];

  __syncthreads();

  short* Pw = P[wave];

  for (int tt = 0; tt < 4; ++tt) {
    int tile = wave + tt * 4;   // row-tile index 0..15
    int m0 = tile * 16;
    bf16x8 qf[2];
#pragma unroll
    for (int ks = 0; ks < 2; ++ks)
      qf[ks] = *(const bf16x8*)&QKV[base + (long)(m0 + lr) * C3 + ks * 32 + lg * 8];

    f32x4 zero4 = {0.f, 0.f, 0.f, 0.f};
    f32x4 accs[16];
#pragma unroll
    for (int n = 0; n < 16; ++n) accs[n] = zero4;

#pragma unroll
    for (int n = 0; n < 16; ++n) {
      if (n <= tile) {
        accs[n] = __builtin_amdgcn_mfma_f32_16x16x32_bf16(qf[0], kf[n][0], accs[n], 0, 0, 0);
        accs[n] = __builtin_amdgcn_mfma_f32_16x16x32_bf16(qf[1], kf[n][1], accs[n], 0, 0, 0);
      }
    }

    float lsum[4];
#pragma unroll
    for (int r = 0; r < 4; ++r) {
      int qrow = m0 + lg * 4 + r;
      float m = -1e30f;
#pragma unroll
      for (int n = 0; n < 16; ++n) {
        if (n <= tile) {
          int col = n * 16 + lr;
          float v = accs[n][r] * 0.125f;
          v = (col <= qrow) ? v : -1e30f;
          accs[n][r] = v;
          m = fmaxf(m, v);
        }
      }
#pragma unroll
      for (int o = 1; o < 16; o <<= 1) m = fmaxf(m, __shfl_xor(m, o));
      float s = 0.f;
#pragma unroll
      for (int n = 0; n < 16; ++n) {
        if (n <= tile) {
          float p = __expf(accs[n][r] - m);
          accs[n][r] = p;
          s += p;
        }
      }
#pragma unroll
      for (int o = 1; o < 16; o <<= 1) s += __shfl_xor(s, o);
      lsum[r] = s;
    }

    int ktmax = (tile * 16 + 15) >> 5;
    int nlim = 2 * (ktmax + 1);   // exact P column-tile range PV will read
#pragma unroll
    for (int n = 0; n < 16; ++n) {
      if (n < nlim) {
#pragma unroll
        for (int r = 0; r < 4; ++r) {
          int rr = lg * 4 + r, cc = n * 16 + lr;
          float pv = (n <= tile) ? accs[n][r] : 0.0f;
          Pw[rr * 256 + (((cc >> 3) ^ (rr & 7)) << 3) + (cc & 7)] = f2bf(pv);
        }
      }
    }
    asm volatile("s_waitcnt lgkmcnt(0)" ::: "memory");
    __builtin_amdgcn_sched_barrier(0);

    f32x4 yacc[4];
#pragma unroll
    for (int n2 = 0; n2 < 4; ++n2) yacc[n2] = zero4;
#pragma unroll
    for (int kt = 0; kt < 8; ++kt) {
      if (kt <= ktmax) {
        int ac = kt * 32 + lg * 8;
        bf16x8 pa = *(bf16x8*)&Pw[lr * 256 + (((ac >> 3) ^ (lr & 7)) << 3)];
#pragma unroll
        for (int n2 = 0; n2 < 4; ++n2) {
          int vn = n2 * 16 + lr;
          bf16x8 vb = *(bf16x8*)&Vt[vn * 256 + (((ac >> 3) ^ (vn & 7)) << 3)];
          yacc[n2] = __builtin_amdgcn_mfma_f32_16x16x32_bf16(pa, vb, yacc[n2], 0, 0, 0);
        }
      }
    }

#pragma unroll
    for (int n2 = 0; n2 < 4; ++n2) {
#pragma unroll
      for (int r = 0; r < 4; ++r) {
        int row = m0 + lg * 4 + r, d = n2 * 16 + lr;
        float yv = yacc[n2][r] / lsum[r];
        Y[((long)(bg * LS + row)) * C0 + h * HD + d] = f2bf(yv);
      }
    }
    asm volatile("s_waitcnt lgkmcnt(0)" ::: "memory");
    __builtin_amdgcn_sched_barrier(0);
  }
}

extern "C" void kernel_launch(void* const* d_in, const int* in_sizes, int n_in,
                              void* d_out, int out_size, void* d_ws, size_t ws_size,
                              hipStream_t stream) {
  (void)in_sizes; (void)n_in; (void)out_size; (void)ws_size;
  const float* x = (const float*)d_in[0];
  const float* w_qkv = (const float*)d_in[1];
  const float* w_ln = (const float*)d_in[2];
  const float* w_proj = (const float*)d_in[3];
  float* out = (float*)d_out;

  char* ws = (char*)d_ws;
  short* Xb      = (short*)(ws + 0);                    // 32768*768*2   = 50331648
  short* QKV     = (short*)(ws + 50331648);             // 32768*2304*2  = 150994944
  short* Yb      = (short*)(ws + 201326592);            // 32768*768*2   = 50331648
  short* WqkvT   = (short*)(ws + 251658240);            // [2304][768] bf16
  short* WprojT  = (short*)(ws + 255197184);            // [768][768] bf16
  float* cost    = (float*)(ws + 256376832);
  float* sint    = (float*)(ws + 256442368);

  cast_kernel<<<2048, 256, 0, stream>>>(x, Xb, (4 * 8192 * C0) / 4);
  cast_transpose_kernel<<<dim3(C3 / 32, C0 / 32), 256, 0, stream>>>(w_qkv, WqkvT, C0, C3);
  cast_transpose_kernel<<<dim3(C0 / 32, C0 / 32), 256, 0, stream>>>(w_proj, WprojT, C0, C0);
  rope_tab_kernel<<<256, 64, 0, stream>>>(cost, sint);

  // QKV = X @ Wqkv  (A[32768][768] x Bt[2304][768])
  gemm_kernel<0><<<dim3(C3 / 128, 32768 / 128), 256, 0, stream>>>(Xb, WqkvT, QKV, C3, C0);
  norm_rope_kernel<<<32768, 384, 0, stream>>>(QKV, w_ln, cost, sint);
  attn_kernel<<<128 * NH, 256, 0, stream>>>(QKV, Yb);
  // out = Y @ Wproj (fp32 out)
  gemm_kernel<1><<<dim3(C0 / 128, 32768 / 128), 256, 0, stream>>>(Yb, WprojT, out, C0, C0);
}

// Round 4
// 352.560 us; speedup vs baseline: 2.5877x; 1.3581x over previous
//
#include <hip/hip_runtime.h>
#include <math.h>

typedef __attribute__((ext_vector_type(8))) short bf16x8;
typedef __attribute__((ext_vector_type(4))) short bf16x4;
typedef __attribute__((ext_vector_type(2))) short bf16x2;
typedef __attribute__((ext_vector_type(4))) float f32x4;

#define NH 12
#define HD 64
#define C0 768
#define C3 2304
#define LS 256

static __device__ __forceinline__ float bf2f(short u) {
  union { unsigned int i; float f; } c;
  c.i = ((unsigned int)(unsigned short)u) << 16;
  return c.f;
}
static __device__ __forceinline__ short f2bf(float f) {
  union { float f; unsigned int i; } c; c.f = f;
  unsigned int x = c.i;
  x += 0x7fffu + ((x >> 16) & 1u);
  return (short)(x >> 16);
}
static __device__ __forceinline__ unsigned pk2(float a, float b) {
  return (unsigned)(unsigned short)f2bf(a) | ((unsigned)(unsigned short)f2bf(b) << 16);
}

// async global->LDS, 16B per lane; LDS dest is wave-uniform base + lane*16
static __device__ __forceinline__ void gload_lds16(const short* g, const short* l) {
  unsigned long long ga = (unsigned long long)g;
  unsigned int la = (unsigned int)(unsigned long long)l;
  __builtin_amdgcn_global_load_lds(
      (const __attribute__((address_space(1))) void*)ga,
      (__attribute__((address_space(3))) void*)la, 16, 0, 0);
}

// ---------------- cast fp32 -> bf16 (vectorized) ----------------
__global__ __launch_bounds__(256) void cast_kernel(const float* __restrict__ in,
                                                   short* __restrict__ out, int nquads) {
  int i = blockIdx.x * blockDim.x + threadIdx.x;
  int stride = gridDim.x * blockDim.x;
  for (; i < nquads; i += stride) {
    float4 v = ((const float4*)in)[i];
    bf16x4 o = { f2bf(v.x), f2bf(v.y), f2bf(v.z), f2bf(v.w) };
    ((bf16x4*)out)[i] = o;
  }
}

// ---------------- cast + transpose: in[K][N] fp32 -> out[N][K] bf16 ----------------
__global__ __launch_bounds__(256) void cast_transpose_kernel(const float* __restrict__ in,
                                                             short* __restrict__ out,
                                                             int K, int N) {
  __shared__ float tile[32][33];
  int n0 = blockIdx.x * 32, k0 = blockIdx.y * 32;
  int tx = threadIdx.x & 31, ty = threadIdx.x >> 5;
#pragma unroll
  for (int i = 0; i < 32; i += 8)
    tile[ty + i][tx] = in[(long)(k0 + ty + i) * N + n0 + tx];
  __syncthreads();
#pragma unroll
  for (int i = 0; i < 32; i += 8)
    out[(long)(n0 + ty + i) * K + k0 + tx] = f2bf(tile[tx][ty + i]);
}

// ---------------- RoPE table ----------------
__global__ void rope_tab_kernel(float* __restrict__ cost, float* __restrict__ sint) {
  int t = blockIdx.x, d = threadIdx.x;
  int i = d & 31;
  float freq = powf(10000.0f, -(float)(4 * i + 1) / 64.0f);
  float th = (float)t * freq;
  cost[t * 64 + d] = cosf(th);
  sint[t * 64 + d] = sinf(th);
}

// ---------------- bf16 MFMA GEMM (m97 structure), unchanged from round 3 ----------------
template <int OUT_F32>
__global__ __launch_bounds__(256) void gemm_kernel(const short* __restrict__ A,
                                                   const short* __restrict__ Bt,
                                                   void* __restrict__ Cout,
                                                   int N, int K) {
  __shared__ short As[128 * 64];
  __shared__ short Bs[128 * 64];
  int bn = blockIdx.x, bm = blockIdx.y;
  int t = threadIdx.x, lane = t & 63, wave = t >> 6;
  int lr = lane & 15, lg = lane >> 4;
  int wm = (wave >> 1) * 64, wn = (wave & 1) * 64;
  const short* Abase = A + (long)bm * 128 * K;
  const short* Bbase = Bt + (long)bn * 128 * K;

  f32x4 zero4 = {0.f, 0.f, 0.f, 0.f};
  f32x4 acc[4][4];
#pragma unroll
  for (int m = 0; m < 4; ++m)
#pragma unroll
    for (int n = 0; n < 4; ++n) acc[m][n] = zero4;

  int srow[4], scol[4];
#pragma unroll
  for (int i = 0; i < 4; ++i) {
    int q = i * 256 + t;
    int r = q >> 3, cp = q & 7;
    srow[i] = r;
    scol[i] = (cp ^ (r & 7)) * 8;
  }

  for (int kt = 0; kt < K / 64; ++kt) {
    int k0 = kt * 64;
#pragma unroll
    for (int i = 0; i < 4; ++i) {
      int q = i * 256 + t;
      gload_lds16(Abase + (long)srow[i] * K + k0 + scol[i], &As[q * 8]);
      gload_lds16(Bbase + (long)srow[i] * K + k0 + scol[i], &Bs[q * 8]);
    }
    asm volatile("s_waitcnt vmcnt(0)" ::: "memory");
    __syncthreads();

#pragma unroll
    for (int s = 0; s < 2; ++s) {
      bf16x8 af[4], bfv[4];
#pragma unroll
      for (int m = 0; m < 4; ++m) {
        int row = wm + m * 16 + lr;
        af[m] = *(bf16x8*)&As[row * 64 + (((s * 4 + lg) ^ (row & 7)) << 3)];
      }
#pragma unroll
      for (int n = 0; n < 4; ++n) {
        int row = wn + n * 16 + lr;
        bfv[n] = *(bf16x8*)&Bs[row * 64 + (((s * 4 + lg) ^ (row & 7)) << 3)];
      }
#pragma unroll
      for (int m = 0; m < 4; ++m)
#pragma unroll
        for (int n = 0; n < 4; ++n)
          acc[m][n] = __builtin_amdgcn_mfma_f32_16x16x32_bf16(af[m], bfv[n], acc[m][n], 0, 0, 0);
    }
    __syncthreads();
  }

  long crow0 = (long)bm * 128 + wm;
  long ccol0 = (long)bn * 128 + wn;
#pragma unroll
  for (int m = 0; m < 4; ++m)
#pragma unroll
    for (int n = 0; n < 4; ++n)
#pragma unroll
      for (int r = 0; r < 4; ++r) {
        long row = crow0 + m * 16 + lg * 4 + r;
        long col = ccol0 + n * 16 + lr;
        float v = acc[m][n][r];
        if (OUT_F32) ((float*)Cout)[row * N + col] = v;
        else ((short*)Cout)[row * N + col] = f2bf(v);
      }
}

// ---------------- fused RMSNorm(q,k) + RoPE, in place (unchanged) ----------------
__global__ __launch_bounds__(384) void norm_rope_kernel(short* __restrict__ QKV,
    const float* __restrict__ w_ln, const float* __restrict__ cost,
    const float* __restrict__ sint) {
  int row = blockIdx.x;
  int t = row & 255;
  int i = threadIdx.x;
  long base = (long)row * C3;
  bf16x2 q2 = *(bf16x2*)&QKV[base + 2 * i];
  bf16x2 k2 = *(bf16x2*)&QKV[base + C0 + 2 * i];
  float qa = bf2f(q2.x), qb = bf2f(q2.y);
  float ka = bf2f(k2.x), kb = bf2f(k2.y);
  float sq = qa * qa + qb * qb;
  float sk = ka * ka + kb * kb;
#pragma unroll
  for (int o = 32; o > 0; o >>= 1) {
    sq += __shfl_down(sq, o);
    sk += __shfl_down(sk, o);
  }
  __shared__ float red[2][6];
  int wv = i >> 6;
  if ((i & 63) == 0) { red[0][wv] = sq; red[1][wv] = sk; }
  __syncthreads();
  float s0 = 0.f, s1 = 0.f;
#pragma unroll
  for (int w = 0; w < 6; ++w) { s0 += red[0][w]; s1 += red[1][w]; }
  float rq = rsqrtf(s0 * (1.0f / 768.0f) + 1e-6f);
  float rk = rsqrtf(s1 * (1.0f / 768.0f) + 1e-6f);
  float wl0 = w_ln[2 * i], wl1 = w_ln[2 * i + 1];
  float qn0 = qa * rq * wl0, qn1 = qb * rq * wl1;
  float kn0 = ka * rk * wl0, kn1 = kb * rk * wl1;
  int d0 = (2 * i) & 63;
  float c0 = cost[t * 64 + d0], c1 = cost[t * 64 + d0 + 1];
  float s0r = sint[t * 64 + d0], s1r = sint[t * 64 + d0 + 1];
  bf16x2 qo, ko;
  qo.x = f2bf(qn0 * c0 - qn1 * s0r);
  qo.y = f2bf(qn1 * c1 + qn0 * s1r);
  ko.x = f2bf(kn0 * c0 - kn1 * s0r);
  ko.y = f2bf(kn1 * c1 + kn0 * s1r);
  *(bf16x2*)&QKV[base + 2 * i] = qo;
  *(bf16x2*)&QKV[base + C0 + 2 * i] = ko;
}

// ---------------- block-causal attention, restructured ----------------
// 512 threads (8 waves) per (bg,head). K in LDS (shared, swizzled, gload_lds);
// V^T in LDS; swapped QK^T (S^T = mfma(K,Q)) -> lane-local softmax rows;
// P redistributed to PV A-frags via 8 ds_bpermute per 32-k chunk (no P LDS).
// Wave w handles tiles {w, 15-w} (balanced). No LDS hazards after the one barrier.
__global__ __launch_bounds__(512, 3) void attn_kernel(const short* __restrict__ QKV,
                                                      short* __restrict__ Y) {
  __shared__ short Ks[256 * 64];   // 32 KB, [k][d] with 16B-chunk XOR swizzle
  __shared__ short Vt[64 * 256];   // 32 KB, [d][k] with 16B-chunk XOR swizzle
  int blk = blockIdx.x;
  int bg = blk / NH, h = blk % NH;
  const long base = (long)bg * LS * C3 + h * HD;
  int tid = threadIdx.x, lane = tid & 63, wave = tid >> 6;
  int lr = lane & 15, lg = lane >> 4;

  // stage K: 2048 x 16B chunks, linear LDS dest, pre-swizzled global source
#pragma unroll
  for (int it = 0; it < 4; ++it) {
    int q = it * 512 + tid;
    int row = q >> 3, cp = q & 7;
    int gcp = cp ^ (row & 7);
    gload_lds16(QKV + base + (long)row * C3 + C0 + gcp * 8, &Ks[q * 8]);
  }
  // stage V transposed + swizzled (reg path)
#pragma unroll
  for (int it = 0; it < 8; ++it) {
    int e = tid * 4 + it * 2048;
    int k = e >> 6, n = e & 63;
    bf16x4 v = *(const bf16x4*)&QKV[base + (long)k * C3 + 2 * C0 + n];
#pragma unroll
    for (int j = 0; j < 4; ++j) {
      int nn = n + j;
      Vt[nn * 256 + (((k >> 3) ^ (nn & 7)) << 3) + (k & 7)] = v[j];
    }
  }
  asm volatile("s_waitcnt vmcnt(0)" ::: "memory");
  __syncthreads();

  // bpermute gather addresses (derived for 16x16 C-layout; verified element-wise):
  // target lane (LR=lr, LG=lg) A-frag word w reads src lane ((LG&1)*2 + (w>>1))*16 + LR
  int addrA = (((lane >> 4) & 1) * 32 + lr) * 4;
  int addrB = addrA + 64;
  bool selhi = (lane & 32) != 0;  // LG>>1: picks n1 over n0

  for (int tt = 0; tt < 2; ++tt) {
    int tile = (tt == 0) ? wave : (15 - wave);
    int m0 = tile * 16;
    bf16x8 qf[2];
#pragma unroll
    for (int ks = 0; ks < 2; ++ks)
      qf[ks] = *(const bf16x8*)&QKV[base + (long)(m0 + lr) * C3 + ks * 32 + lg * 8];

    f32x4 zero4 = {0.f, 0.f, 0.f, 0.f};
    f32x4 accs[16];
#pragma unroll
    for (int n = 0; n < 16; ++n) accs[n] = zero4;

    // S^T = K Q^T : accs[n] holds S at (k = n*16 + lg*4 + r, q = m0 + lr)
    __builtin_amdgcn_s_setprio(1);
#pragma unroll
    for (int n = 0; n < 16; ++n) {
      if (n <= tile) {
        int row = n * 16 + lr, sw = row & 7;
        bf16x8 k0 = *(bf16x8*)&Ks[row * 64 + ((lg ^ sw) << 3)];
        bf16x8 k1 = *(bf16x8*)&Ks[row * 64 + (((4 + lg) ^ sw) << 3)];
        accs[n] = __builtin_amdgcn_mfma_f32_16x16x32_bf16(k0, qf[0], accs[n], 0, 0, 0);
        accs[n] = __builtin_amdgcn_mfma_f32_16x16x32_bf16(k1, qf[1], accs[n], 0, 0, 0);
      }
    }
    __builtin_amdgcn_s_setprio(0);

    // softmax over k for q=m0+lr: mask diagonal, lane-local max/sum + xor16/32
    float mloc = -1e30f;
#pragma unroll
    for (int n = 0; n < 16; ++n) {
      if (n <= tile) {
#pragma unroll
        for (int r = 0; r < 4; ++r) {
          float v = accs[n][r];
          if (n == tile) v = (lg * 4 + r <= lr) ? v : -1e30f;
          accs[n][r] = v;
          mloc = fmaxf(mloc, v);
        }
      }
    }
    mloc = fmaxf(mloc, __shfl_xor(mloc, 16));
    mloc = fmaxf(mloc, __shfl_xor(mloc, 32));
    float s = 0.f;
#pragma unroll
    for (int n = 0; n < 16; ++n) {
      if (n <= tile) {
#pragma unroll
        for (int r = 0; r < 4; ++r) {
          float p = __expf((accs[n][r] - mloc) * 0.125f);
          accs[n][r] = p;
          s += p;
        }
      }
    }
    s += __shfl_xor(s, 16);
    s += __shfl_xor(s, 32);
    float rs = 1.0f / s;
    // redistribute 1/sum to epilogue layout (row q = m0 + lg*4 + r)
    float rv[4];
#pragma unroll
    for (int r = 0; r < 4; ++r) {
      union { float f; int i; } c; c.f = rs;
      union { int i; float f; } o;
      o.i = __builtin_amdgcn_ds_bpermute((lg * 4 + r) * 4, c.i);
      rv[r] = o.f;
    }

    // PV: per 32-k chunk, gather A-frag via bpermute, MFMA with Vt
    int ktmax = (m0 + 15) >> 5;
    f32x4 yacc[4];
#pragma unroll
    for (int n2 = 0; n2 < 4; ++n2) yacc[n2] = zero4;
#pragma unroll
    for (int kt = 0; kt < 8; ++kt) {
      if (kt <= ktmax) {
        int n0 = 2 * kt, n1 = 2 * kt + 1;
        unsigned a01_0 = pk2(accs[n0][0], accs[n0][1]);
        unsigned a23_0 = pk2(accs[n0][2], accs[n0][3]);
        unsigned a01_1 = (n1 <= tile) ? pk2(accs[n1][0], accs[n1][1]) : 0u;
        unsigned a23_1 = (n1 <= tile) ? pk2(accs[n1][2], accs[n1][3]) : 0u;
        union { unsigned u[4]; bf16x8 v; } af;
        unsigned g0a = (unsigned)__builtin_amdgcn_ds_bpermute(addrA, (int)a01_0);
        unsigned g0b = (unsigned)__builtin_amdgcn_ds_bpermute(addrA, (int)a01_1);
        unsigned g1a = (unsigned)__builtin_amdgcn_ds_bpermute(addrA, (int)a23_0);
        unsigned g1b = (unsigned)__builtin_amdgcn_ds_bpermute(addrA, (int)a23_1);
        unsigned g2a = (unsigned)__builtin_amdgcn_ds_bpermute(addrB, (int)a01_0);
        unsigned g2b = (unsigned)__builtin_amdgcn_ds_bpermute(addrB, (int)a01_1);
        unsigned g3a = (unsigned)__builtin_amdgcn_ds_bpermute(addrB, (int)a23_0);
        unsigned g3b = (unsigned)__builtin_amdgcn_ds_bpermute(addrB, (int)a23_1);
        af.u[0] = selhi ? g0b : g0a;
        af.u[1] = selhi ? g1b : g1a;
        af.u[2] = selhi ? g2b : g2a;
        af.u[3] = selhi ? g3b : g3a;
        int ac = kt * 32 + lg * 8;
        __builtin_amdgcn_s_setprio(1);
#pragma unroll
        for (int n2 = 0; n2 < 4; ++n2) {
          int vn = n2 * 16 + lr;
          bf16x8 vb = *(bf16x8*)&Vt[vn * 256 + (((ac >> 3) ^ (vn & 7)) << 3)];
          yacc[n2] = __builtin_amdgcn_mfma_f32_16x16x32_bf16(af.v, vb, yacc[n2], 0, 0, 0);
        }
        __builtin_amdgcn_s_setprio(0);
      }
    }

    // epilogue: Y row q = m0 + lg*4 + r, col d = n2*16 + lr
#pragma unroll
    for (int n2 = 0; n2 < 4; ++n2) {
#pragma unroll
      for (int r = 0; r < 4; ++r) {
        int row = m0 + lg * 4 + r, d = n2 * 16 + lr;
        Y[((long)(bg * LS + row)) * C0 + h * HD + d] = f2bf(yacc[n2][r] * rv[r]);
      }
    }
  }
}

extern "C" void kernel_launch(void* const* d_in, const int* in_sizes, int n_in,
                              void* d_out, int out_size, void* d_ws, size_t ws_size,
                              hipStream_t stream) {
  (void)in_sizes; (void)n_in; (void)out_size; (void)ws_size;
  const float* x = (const float*)d_in[0];
  const float* w_qkv = (const float*)d_in[1];
  const float* w_ln = (const float*)d_in[2];
  const float* w_proj = (const float*)d_in[3];
  float* out = (float*)d_out;

  char* ws = (char*)d_ws;
  short* Xb      = (short*)(ws + 0);
  short* QKV     = (short*)(ws + 50331648);
  short* Yb      = (short*)(ws + 201326592);
  short* WqkvT   = (short*)(ws + 251658240);
  short* WprojT  = (short*)(ws + 255197184);
  float* cost    = (float*)(ws + 256376832);
  float* sint    = (float*)(ws + 256442368);

  cast_kernel<<<2048, 256, 0, stream>>>(x, Xb, (4 * 8192 * C0) / 4);
  cast_transpose_kernel<<<dim3(C3 / 32, C0 / 32), 256, 0, stream>>>(w_qkv, WqkvT, C0, C3);
  cast_transpose_kernel<<<dim3(C0 / 32, C0 / 32), 256, 0, stream>>>(w_proj, WprojT, C0, C0);
  rope_tab_kernel<<<256, 64, 0, stream>>>(cost, sint);

  gemm_kernel<0><<<dim3(C3 / 128, 32768 / 128), 256, 0, stream>>>(Xb, WqkvT, QKV, C3, C0);
  norm_rope_kernel<<<32768, 384, 0, stream>>>(QKV, w_ln, cost, sint);
  attn_kernel<<<128 * NH, 512, 0, stream>>>(QKV, Yb);
  gemm_kernel<1><<<dim3(C0 / 128, 32768 / 128), 256, 0, stream>>>(Yb, WprojT, out, C0, C0);
}